// Round 4
// baseline (757.246 us; speedup 1.0000x reference)
//
#include <hip/hip_runtime.h>
#include <hip/hip_bf16.h>
#include <stdint.h>

#define M_TOK 4096
#define DDIM  2048
#define HDIM  2816
#define NEXP  8
#define PMAX  10240     // 40 * 256 >= 8192 + 8*255
#define MAXTILES 40
#define NB1   22        // HDIM / 128 gate-col blocks (B tile = 128 gate + 128 up rows)
#define NB2   8         // DDIM / 256
#define NT1   64        // DDIM / 32
#define NT2   88        // HDIM / 32

typedef __attribute__((ext_vector_type(8))) short short8;
typedef __attribute__((ext_vector_type(4))) float f32x4;

#define GLD16(g, l) __builtin_amdgcn_global_load_lds(                              \
    (const __attribute__((address_space(1))) unsigned int*)(g),                    \
    (__attribute__((address_space(3))) unsigned int*)(l), 16, 0, 0)

#define VMCNT(n) asm volatile("s_waitcnt vmcnt(" #n ")" ::: "memory")

__device__ __forceinline__ unsigned short f2bf(float f) {
  unsigned int u = __float_as_uint(f);
  u += 0x7fffu + ((u >> 16) & 1u);
  return (unsigned short)(u >> 16);
}
__device__ __forceinline__ float bf2f(unsigned short u) {
  return __uint_as_float(((unsigned)u) << 16);
}

// ---- shared 2-phase K-tile schedule (BK=32, 4 LDS banks, stage 3 ahead) ----
// Phase: vmcnt [P0 only] -> entry barrier -> ds_reads (same-phase operands) +
// stage (2 gloads, bank (KT+3)&3) -> exit barrier -> setprio(1) 16 MFMA.
// Safety: vmcnt(8) before entry barrier retires every wave's tile-KT loads;
// exit barrier follows each wave's MFMA cluster whose operand waits drain its
// ds_reads, so the stage into bank (KT+3)&3 == (KT-1)&3 can't race readers.
#define GP0(KT, VM, STG)                                                         \
  { VMCNT(VM);                                                                   \
    __builtin_amdgcn_s_barrier();                                                \
    asm volatile("" ::: "memory");                                               \
    { const char* ab_ = ldsp + ((KT) & 3) * 16384;                               \
      const char* bb_ = ldsp + 65536 + ((KT) & 3) * 16384;                       \
      _Pragma("unroll") for (int mi = 0; mi < 4; ++mi)                           \
        av[mi] = *(const short8*)(ab_ + aoff[mi]);                               \
      _Pragma("unroll") for (int ni = 0; ni < 4; ++ni)                           \
        bv[ni] = *(const short8*)(bb_ + boff[ni]);                               \
      if (STG) { size_t kb_ = (size_t)((KT) + 3) * 64;                           \
        char* d_ = ldsp + (((KT) + 3) & 3) * 16384;                              \
        GLD16(aS0 + kb_, d_ + aD0); GLD16(aS1 + kb_, d_ + aD1); }                \
    }                                                                            \
    asm volatile("" ::: "memory");                                               \
    __builtin_amdgcn_s_barrier();                                                \
    __builtin_amdgcn_s_setprio(1);                                               \
    _Pragma("unroll") for (int mi = 0; mi < 4; ++mi)                             \
      _Pragma("unroll") for (int ni = 0; ni < 4; ++ni)                           \
        acc[mi][ni] = __builtin_amdgcn_mfma_f32_16x16x32_bf16(av[mi], bv[ni], acc[mi][ni], 0, 0, 0); \
    __builtin_amdgcn_s_setprio(0); }

#define GP1(KT, STG)                                                             \
  { __builtin_amdgcn_s_barrier();                                                \
    asm volatile("" ::: "memory");                                               \
    { const char* ab_ = ldsp + ((KT) & 3) * 16384;                               \
      _Pragma("unroll") for (int mi = 0; mi < 4; ++mi)                           \
        av[mi] = *(const short8*)(ab_ + aoff[4 + mi]);                           \
      if (STG) { size_t kb_ = (size_t)((KT) + 3) * 64;                           \
        char* d_ = ldsp + 65536 + (((KT) + 3) & 3) * 16384;                      \
        GLD16(bS0 + kb_, d_ + aD0); GLD16(bS1 + kb_, d_ + aD1); }                \
    }                                                                            \
    asm volatile("" ::: "memory");                                               \
    __builtin_amdgcn_s_barrier();                                                \
    __builtin_amdgcn_s_setprio(1);                                               \
    _Pragma("unroll") for (int mi = 0; mi < 4; ++mi)                             \
      _Pragma("unroll") for (int ni = 0; ni < 4; ++ni)                           \
        acc[4 + mi][ni] = __builtin_amdgcn_mfma_f32_16x16x32_bf16(av[mi], bv[ni], acc[4 + mi][ni], 0, 0, 0); \
    __builtin_amdgcn_s_setprio(0); }

// ---------------- fp32 -> bf16 bulk convert ----------------
__global__ void cvt_bf16_k(const float4* __restrict__ in, ushort4* __restrict__ out, int n4) {
  int stride = gridDim.x * blockDim.x;
  for (int i = blockIdx.x * blockDim.x + threadIdx.x; i < n4; i += stride) {
    float4 v = in[i];
    ushort4 o;
    o.x = f2bf(v.x); o.y = f2bf(v.y); o.z = f2bf(v.z); o.w = f2bf(v.w);
    out[i] = o;
  }
}

// ---------------- init ----------------
__global__ void init_k(int* __restrict__ tok, int* __restrict__ counts, int* __restrict__ cursors) {
  int i = blockIdx.x * blockDim.x + threadIdx.x;
  if (i < PMAX) tok[i] = -1;
  if (i < NEXP) { counts[i] = 0; cursors[i] = 0; }
}

// ---------------- router (fused x->bf16 conversion) ----------------
__global__ __launch_bounds__(256) void router_k(const float4* __restrict__ x4,
                                                const float4* __restrict__ rw4,
                                                ushort4* __restrict__ xb4,
                                                float* __restrict__ wgt,
                                                int* __restrict__ eid,
                                                int* __restrict__ counts) {
  int lane = threadIdx.x & 63;
  int wv = threadIdx.x >> 6;
  int t = blockIdx.x * 4 + wv;
  int base = t * (DDIM / 4);
  float acc[NEXP];
#pragma unroll
  for (int e = 0; e < NEXP; ++e) acc[e] = 0.f;
#pragma unroll
  for (int j = 0; j < DDIM / 4 / 64; ++j) {
    float4 v = x4[base + j * 64 + lane];
    ushort4 o;
    o.x = f2bf(v.x); o.y = f2bf(v.y); o.z = f2bf(v.z); o.w = f2bf(v.w);
    xb4[base + j * 64 + lane] = o;
#pragma unroll
    for (int e = 0; e < NEXP; ++e) {
      float4 w = rw4[e * (DDIM / 4) + j * 64 + lane];
      acc[e] += v.x * w.x + v.y * w.y + v.z * w.z + v.w * w.w;
    }
  }
#pragma unroll
  for (int e = 0; e < NEXP; ++e) {
#pragma unroll
    for (int s = 32; s > 0; s >>= 1) acc[e] += __shfl_xor(acc[e], s, 64);
  }
  if (lane == 0) {
    float mx = acc[0];
#pragma unroll
    for (int e = 1; e < NEXP; ++e) mx = fmaxf(mx, acc[e]);
    float p[NEXP];
#pragma unroll
    for (int e = 0; e < NEXP; ++e) p[e] = expf(acc[e] - mx);
    int e0 = 0; float p0 = p[0];
#pragma unroll
    for (int e = 1; e < NEXP; ++e) if (p[e] > p0) { p0 = p[e]; e0 = e; }
    int e1 = -1; float p1 = -1.f;
#pragma unroll
    for (int e = 0; e < NEXP; ++e) if (e != e0 && p[e] > p1) { p1 = p[e]; e1 = e; }
    float s = p0 + p1;
    wgt[2 * t] = p0 / s; wgt[2 * t + 1] = p1 / s;
    eid[2 * t] = e0;     eid[2 * t + 1] = e1;
    atomicAdd(&counts[e0], 1);
    atomicAdd(&counts[e1], 1);
  }
}

// ---------------- offsets + tile map (256-row tiles, shared by both GEMMs) ----------------
__global__ void offsets_k(const int* __restrict__ counts, int* __restrict__ offs,
                          int* __restrict__ tile2exp, int* __restrict__ tilerow,
                          int* __restrict__ ntiles) {
  if (threadIdx.x == 0 && blockIdx.x == 0) {
    int o = 0, nt = 0;
    for (int e = 0; e < NEXP; ++e) {
      offs[e] = o;
      int c = counts[e];
      int pt = (c + 255) >> 8;
      for (int i = 0; i < pt; ++i) { tile2exp[nt] = e; tilerow[nt] = o + i * 256; ++nt; }
      o += pt << 8;
    }
    offs[NEXP] = o;
    ntiles[0] = nt;
  }
}

// ---------------- scatter ----------------
__global__ void scatter_k(const int* __restrict__ eid, const int* __restrict__ offs,
                          int* __restrict__ cursors, int* __restrict__ tok,
                          int* __restrict__ slot) {
  int t = blockIdx.x * blockDim.x + threadIdx.x;
  if (t >= M_TOK) return;
#pragma unroll
  for (int k = 0; k < 2; ++k) {
    int e = eid[2 * t + k];
    int p = offs[e] + atomicAdd(&cursors[e], 1);
    tok[p] = t;
    slot[2 * t + k] = p;
  }
}

// =============== GEMM1: 256 slots x (128 gate + 128 up), K=2048 ===============
__global__ __launch_bounds__(512, 1) void gemm1_k(const unsigned short* __restrict__ xb,
                                                  const unsigned short* __restrict__ w1b,
                                                  const int* __restrict__ tok,
                                                  const int* __restrict__ tile2exp,
                                                  const int* __restrict__ tilerow,
                                                  const int* __restrict__ ntiles,
                                                  unsigned short* __restrict__ h) {
  __shared__ char ldsp[131072];
  int mt = blockIdx.x;
  if (mt >= ntiles[0]) return;
  int e = tile2exp[mt], r0 = tilerow[mt];
  int n0 = blockIdx.y * 128;
  int tid = threadIdx.x, lane = tid & 63;
  int wv = tid >> 6, wm = wv >> 2, wn = wv & 3;
  int l15 = lane & 15, g = lane >> 4;

  // staging: linear LDS dest slots tid, 512+tid; inverse-swizzled global granule
  int row0 = tid >> 2, g0 = (tid & 3) ^ ((row0 >> 1) & 3);   // rows 0..127
  int row1 = row0 + 128;                                      // rows 128..255 (same granule swizzle)
  int t0 = tok[r0 + row0]; if (t0 < 0) t0 = 0;
  int t1 = tok[r0 + row1]; if (t1 < 0) t1 = 0;
  const char* aS0 = (const char*)xb + (size_t)t0 * (DDIM * 2) + g0 * 16;
  const char* aS1 = (const char*)xb + (size_t)t1 * (DDIM * 2) + g0 * 16;
  size_t w1r0 = (size_t)e * (2 * HDIM) +
                (row0 < 128 ? (size_t)(n0 + row0) : (size_t)(HDIM + n0 + row0 - 128));
  size_t w1r1 = (size_t)e * (2 * HDIM) + (size_t)(HDIM + n0 + row1 - 128);
  const char* bS0 = (const char*)w1b + w1r0 * (DDIM * 2) + g0 * 16;
  const char* bS1 = (const char*)w1b + w1r1 * (DDIM * 2) + g0 * 16;
  int aD0 = tid * 16, aD1 = 8192 + tid * 16;

  int aoff[8], boff[4];
#pragma unroll
  for (int mi = 0; mi < 8; ++mi) {
    int r = wm * 128 + mi * 16 + l15;
    aoff[mi] = r * 64 + ((g ^ ((r >> 1) & 3)) * 16);
  }
#pragma unroll
  for (int ni = 0; ni < 4; ++ni) {
    int r = wn * 64 + ni * 16 + l15;
    boff[ni] = r * 64 + ((g ^ ((r >> 1) & 3)) * 16);
  }

  f32x4 acc[8][4];
#pragma unroll
  for (int mi = 0; mi < 8; ++mi)
#pragma unroll
    for (int ni = 0; ni < 4; ++ni) acc[mi][ni] = (f32x4)(0.f);

  short8 av[4], bv[4];

  // prologue: stage tiles 0,1,2 (A then B per tile; 12 loads/thread)
#pragma unroll
  for (int t = 0; t < 3; ++t) {
    GLD16(aS0 + (size_t)t * 64, ldsp + t * 16384 + aD0);
    GLD16(aS1 + (size_t)t * 64, ldsp + t * 16384 + aD1);
    GLD16(bS0 + (size_t)t * 64, ldsp + 65536 + t * 16384 + aD0);
    GLD16(bS1 + (size_t)t * 64, ldsp + 65536 + t * 16384 + aD1);
  }

  for (int kt = 0; kt < NT1 - 3; ++kt) { GP0(kt, 8, 1); GP1(kt, 1); }
  GP0(NT1 - 3, 8, 0); GP1(NT1 - 3, 0);
  GP0(NT1 - 2, 4, 0); GP1(NT1 - 2, 0);
  GP0(NT1 - 1, 0, 0); GP1(NT1 - 1, 0);

  // epilogue: cross-wave GLU pairing through LDS (f32 [256][128], XOR-swizzled)
  __syncthreads();
  float* xch = (float*)ldsp;
  int rbase = (lane >> 4) * 4;
  if (wn >= 2) {
    int uc0 = (wn - 2) * 64;
#pragma unroll
    for (int mi = 0; mi < 8; ++mi)
#pragma unroll
      for (int ni = 0; ni < 4; ++ni)
#pragma unroll
        for (int j = 0; j < 4; ++j) {
          int r = wm * 128 + mi * 16 + rbase + j;
          int c = uc0 + ni * 16 + l15;
          int cs = c ^ ((r & 3) << 2) ^ ((r & 1) << 4);
          xch[r * 128 + cs] = acc[mi][ni][j];
        }
  }
  __syncthreads();
  if (wn < 2) {
#pragma unroll
    for (int mi = 0; mi < 8; ++mi)
#pragma unroll
      for (int ni = 0; ni < 4; ++ni)
#pragma unroll
        for (int j = 0; j < 4; ++j) {
          int r = wm * 128 + mi * 16 + rbase + j;
          int c = wn * 64 + ni * 16 + l15;
          int cs = c ^ ((r & 3) << 2) ^ ((r & 1) << 4);
          float gg = acc[mi][ni][j];
          float u = xch[r * 128 + cs];
          float sv = gg / (1.f + expf(-gg));
          h[(size_t)(r0 + r) * HDIM + n0 + c] = f2bf(sv * u);
        }
  }
}

// =============== GEMM2: 256 slots x 256 D-cols, K=2816, yp bf16 ===============
__global__ __launch_bounds__(512, 1) void gemm2_k(const unsigned short* __restrict__ h,
                                                  const unsigned short* __restrict__ w2b,
                                                  const int* __restrict__ tile2exp,
                                                  const int* __restrict__ tilerow,
                                                  const int* __restrict__ ntiles,
                                                  unsigned short* __restrict__ yp) {
  __shared__ char ldsp[131072];
  int mt = blockIdx.x;
  if (mt >= ntiles[0]) return;
  int e = tile2exp[mt], r0 = tilerow[mt];
  int n0 = blockIdx.y * 256;
  int tid = threadIdx.x, lane = tid & 63;
  int wv = tid >> 6, wm = wv >> 2, wn = wv & 3;
  int l15 = lane & 15, g = lane >> 4;

  int row0 = tid >> 2, g0 = (tid & 3) ^ ((row0 >> 1) & 3);
  int row1 = row0 + 128;
  const char* aS0 = (const char*)h + (size_t)(r0 + row0) * (HDIM * 2) + g0 * 16;
  const char* aS1 = (const char*)h + (size_t)(r0 + row1) * (HDIM * 2) + g0 * 16;
  const char* bS0 = (const char*)w2b + ((size_t)e * DDIM + n0 + row0) * (HDIM * 2) + g0 * 16;
  const char* bS1 = (const char*)w2b + ((size_t)e * DDIM + n0 + row1) * (HDIM * 2) + g0 * 16;
  int aD0 = tid * 16, aD1 = 8192 + tid * 16;

  int aoff[8], boff[4];
#pragma unroll
  for (int mi = 0; mi < 8; ++mi) {
    int r = wm * 128 + mi * 16 + l15;
    aoff[mi] = r * 64 + ((g ^ ((r >> 1) & 3)) * 16);
  }
#pragma unroll
  for (int ni = 0; ni < 4; ++ni) {
    int r = wn * 64 + ni * 16 + l15;
    boff[ni] = r * 64 + ((g ^ ((r >> 1) & 3)) * 16);
  }

  f32x4 acc[8][4];
#pragma unroll
  for (int mi = 0; mi < 8; ++mi)
#pragma unroll
    for (int ni = 0; ni < 4; ++ni) acc[mi][ni] = (f32x4)(0.f);

  short8 av[4], bv[4];

#pragma unroll
  for (int t = 0; t < 3; ++t) {
    GLD16(aS0 + (size_t)t * 64, ldsp + t * 16384 + aD0);
    GLD16(aS1 + (size_t)t * 64, ldsp + t * 16384 + aD1);
    GLD16(bS0 + (size_t)t * 64, ldsp + 65536 + t * 16384 + aD0);
    GLD16(bS1 + (size_t)t * 64, ldsp + 65536 + t * 16384 + aD1);
  }

  for (int kt = 0; kt < NT2 - 3; ++kt) { GP0(kt, 8, 1); GP1(kt, 1); }
  GP0(NT2 - 3, 8, 0); GP1(NT2 - 3, 0);
  GP0(NT2 - 2, 4, 0); GP1(NT2 - 2, 0);
  GP0(NT2 - 1, 0, 0); GP1(NT2 - 1, 0);

  int rbase = (lane >> 4) * 4;
#pragma unroll
  for (int mi = 0; mi < 8; ++mi)
#pragma unroll
    for (int ni = 0; ni < 4; ++ni)
#pragma unroll
      for (int j = 0; j < 4; ++j) {
        int r = r0 + wm * 128 + mi * 16 + rbase + j;
        int c = n0 + wn * 64 + ni * 16 + l15;
        yp[(size_t)r * DDIM + c] = f2bf(acc[mi][ni][j]);
      }
}

// ---------------- combine: y = w0*yp[s0] + w1*yp[s1] + bias ----------------
__global__ void combine_k(const unsigned short* __restrict__ yp, const float* __restrict__ wgt,
                          const int* __restrict__ slot, const float* __restrict__ bias,
                          float* __restrict__ out) {
  int idx = blockIdx.x * blockDim.x + threadIdx.x;
  int t = idx >> 8, q = (idx & 255) * 8;
  float w0 = wgt[2 * t], w1 = wgt[2 * t + 1];
  int s0 = slot[2 * t], s1 = slot[2 * t + 1];
  short8 a8 = *(const short8*)(yp + (size_t)s0 * DDIM + q);
  short8 b8 = *(const short8*)(yp + (size_t)s1 * DDIM + q);
  float* op = out + (size_t)t * DDIM + q;
#pragma unroll
  for (int k = 0; k < 8; ++k) {
    float av = bf2f((unsigned short)a8[k]);
    float bv = bf2f((unsigned short)b8[k]);
    op[k] = w0 * av + w1 * bv + bias[q + k];
  }
}

extern "C" void kernel_launch(void* const* d_in, const int* in_sizes, int n_in,
                              void* d_out, int out_size, void* d_ws, size_t ws_size,
                              hipStream_t stream) {
  const float* x    = (const float*)d_in[0];
  const float* w1   = (const float*)d_in[1];
  const float* w2   = (const float*)d_in[2];
  const float* rw   = (const float*)d_in[3];
  const float* bias = (const float*)d_in[4];
  float* out = (float*)d_out;

  char* ws = (char*)d_ws;
  size_t off = 0;
  auto alloc = [&](size_t bytes) -> void* {
    void* p = ws + off;
    off = (off + bytes + 255) & ~(size_t)255;
    return p;
  };
  unsigned short* w1b = (unsigned short*)alloc((size_t)NEXP * 2 * HDIM * DDIM * 2);
  unsigned short* w2b = (unsigned short*)alloc((size_t)NEXP * DDIM * HDIM * 2);
  unsigned short* xb  = (unsigned short*)alloc((size_t)M_TOK * DDIM * 2);
  unsigned short* h   = (unsigned short*)alloc((size_t)PMAX * HDIM * 2);
  unsigned short* yp  = (unsigned short*)alloc((size_t)PMAX * DDIM * 2);
  float* wgt          = (float*)alloc((size_t)M_TOK * 2 * 4);
  int* eid            = (int*)alloc((size_t)M_TOK * 2 * 4);
  int* slot           = (int*)alloc((size_t)M_TOK * 2 * 4);
  int* tok            = (int*)alloc((size_t)PMAX * 4);
  int* counts         = (int*)alloc(64 * 4);
  int* cursors        = (int*)alloc(64 * 4);
  int* offs           = (int*)alloc(64 * 4);
  int* ntiles         = (int*)alloc(64 * 4);
  int* tile2exp       = (int*)alloc(128 * 4);
  int* tilerow        = (int*)alloc(128 * 4);

  hipLaunchKernelGGL(init_k, dim3((PMAX + 255) / 256), dim3(256), 0, stream, tok, counts, cursors);
  hipLaunchKernelGGL(cvt_bf16_k, dim3(2048), dim3(256), 0, stream,
                     (const float4*)w1, (ushort4*)w1b, (int)((size_t)NEXP * 2 * HDIM * DDIM / 4));
  hipLaunchKernelGGL(cvt_bf16_k, dim3(2048), dim3(256), 0, stream,
                     (const float4*)w2, (ushort4*)w2b, (int)((size_t)NEXP * DDIM * HDIM / 4));
  hipLaunchKernelGGL(router_k, dim3(M_TOK / 4), dim3(256), 0, stream,
                     (const float4*)x, (const float4*)rw, (ushort4*)xb, wgt, eid, counts);
  hipLaunchKernelGGL(offsets_k, dim3(1), dim3(64), 0, stream, counts, offs,
                     tile2exp, tilerow, ntiles);
  hipLaunchKernelGGL(scatter_k, dim3((M_TOK + 255) / 256), dim3(256), 0, stream, eid, offs, cursors, tok, slot);
  hipLaunchKernelGGL(gemm1_k, dim3(MAXTILES, NB1), dim3(512), 0, stream,
                     xb, w1b, tok, tile2exp, tilerow, ntiles, h);
  hipLaunchKernelGGL(gemm2_k, dim3(MAXTILES, NB2), dim3(512), 0, stream,
                     h, w2b, tile2exp, tilerow, ntiles, yp);
  hipLaunchKernelGGL(combine_k, dim3(M_TOK * (DDIM / 8) / 256), dim3(256), 0, stream, yp, wgt, slot, bias, out);
}

// Round 5
// 750.644 us; speedup vs baseline: 1.0088x; 1.0088x over previous
//
#include <hip/hip_runtime.h>
#include <hip/hip_bf16.h>
#include <stdint.h>

#define M_TOK 4096
#define DDIM  2048
#define HDIM  2816
#define NEXP  8
#define PMAX  10240     // 40 * 256 >= 8192 + 8*255
#define MAXTILES 40
#define NB1   22        // HDIM / 128 gate-col blocks
#define NB2   8         // DDIM / 256
#define NKT1  32        // DDIM / 64
#define NKT2  44        // HDIM / 64

typedef __attribute__((ext_vector_type(8))) short short8;
typedef __attribute__((ext_vector_type(4))) float f32x4;

#define GLD16(g, l) __builtin_amdgcn_global_load_lds(                              \
    (const __attribute__((address_space(1))) unsigned int*)(g),                    \
    (__attribute__((address_space(3))) unsigned int*)(l), 16, 0, 0)

#define VMCNT(n) asm volatile("s_waitcnt vmcnt(" #n ")" ::: "memory")

__device__ __forceinline__ unsigned short f2bf(float f) {
  unsigned int u = __float_as_uint(f);
  u += 0x7fffu + ((u >> 16) & 1u);
  return (unsigned short)(u >> 16);
}
__device__ __forceinline__ float bf2f(unsigned short u) {
  return __uint_as_float(((unsigned)u) << 16);
}

// ================= 8-phase K-pipeline (m201 port) =================
// LDS: A at 0, B at 65536. Per matrix: dbuf d (K-tile t&1) * 32768 +
// kstep s * 16384 -> 16KB sub-buffer [256 rows][4 granules of 16B],
// row-swizzle g' = g ^ ((r>>1)&3) (2-way bank aliasing = free).
// Phase (t,s,m): read A frags mi=m*4..m*4+3 (+B frags if m==0), issue one
// half-tile stage (2 gloads) into the sub-buffer freed by the PREVIOUS
// phase, barrier, 16 MFMA, barrier. vmcnt(6) once per K-tile (before the
// closing barrier of phase 3) guards the next K-tile's reads.

#define STGA(TT, PP, S)                                                            \
  { size_t kb_ = (size_t)(TT) * 128 + (S) * 64;                                    \
    char* d_ = ldsp + (PP) * 32768 + (S) * 16384;                                  \
    GLD16(aS0 + kb_, d_ + tid * 16); GLD16(aS1 + kb_, d_ + 8192 + tid * 16); }

#define STGB(TT, PP, S)                                                            \
  { size_t kb_ = (size_t)(TT) * 128 + (S) * 64;                                    \
    char* d_ = ldsp + 65536 + (PP) * 32768 + (S) * 16384;                          \
    GLD16(bS0 + kb_, d_ + tid * 16); GLD16(bS1 + kb_, d_ + 8192 + tid * 16); }

#define DSRA(PP, S, M)                                                             \
  { const char* ab_ = ldsp + (PP) * 32768 + (S) * 16384;                           \
    _Pragma("unroll") for (int j_ = 0; j_ < 4; ++j_)                               \
      av[j_] = *(const short8*)(ab_ + aoff[(M) * 4 + j_]); }

#define DSRB(PP, S)                                                                \
  { const char* bb_ = ldsp + 65536 + (PP) * 32768 + (S) * 16384;                   \
    _Pragma("unroll") for (int j_ = 0; j_ < 4; ++j_)                               \
      bv[j_] = *(const short8*)(bb_ + boff[j_]); }

#define MMA16(M)                                                                   \
  { __builtin_amdgcn_s_setprio(1);                                                 \
    _Pragma("unroll") for (int j_ = 0; j_ < 4; ++j_)                               \
      _Pragma("unroll") for (int n_ = 0; n_ < 4; ++n_)                             \
        acc[(M) * 4 + j_][n_] =                                                    \
          __builtin_amdgcn_mfma_f32_16x16x32_bf16(av[j_], bv[n_], acc[(M)*4+j_][n_], 0, 0, 0); \
    __builtin_amdgcn_s_setprio(0); }

#define KTILE(T, P, S0, S1, S2, S3, VM)                                            \
  { /* phase 0: (s0,m0); stage A-Khi(T+1) freed at (T-1,3) */                      \
    DSRA(P, 0, 0); DSRB(P, 0);                                                     \
    if (S0) STGA((T) + 1, (P) ^ 1, 1);                                             \
    __builtin_amdgcn_s_barrier(); MMA16(0); __builtin_amdgcn_s_barrier();          \
    /* phase 1: (s0,m1); stage B-Klo(T+2) freed at phase 0 */                      \
    DSRA(P, 0, 1);                                                                 \
    if (S1) STGB((T) + 2, P, 0);                                                   \
    __builtin_amdgcn_s_barrier(); MMA16(1); __builtin_amdgcn_s_barrier();          \
    /* phase 2: (s1,m0); stage A-Klo(T+2) freed at phase 1 */                      \
    DSRA(P, 1, 0); DSRB(P, 1);                                                     \
    if (S2) STGA((T) + 2, P, 0);                                                   \
    __builtin_amdgcn_s_barrier(); MMA16(0); __builtin_amdgcn_s_barrier();          \
    /* phase 3: (s1,m1); stage B-Khi(T+2) freed at phase 2; vmcnt per K-tile */    \
    DSRA(P, 1, 1);                                                                 \
    if (S3) STGB((T) + 2, P, 1);                                                   \
    __builtin_amdgcn_s_barrier(); MMA16(1);                                        \
    VMCNT(VM);                                                                     \
    __builtin_amdgcn_s_barrier(); }

// ---------------- fp32 -> bf16 bulk convert ----------------
__global__ void cvt_bf16_k(const float4* __restrict__ in, ushort4* __restrict__ out, int n4) {
  int stride = gridDim.x * blockDim.x;
  for (int i = blockIdx.x * blockDim.x + threadIdx.x; i < n4; i += stride) {
    float4 v = in[i];
    ushort4 o;
    o.x = f2bf(v.x); o.y = f2bf(v.y); o.z = f2bf(v.z); o.w = f2bf(v.w);
    out[i] = o;
  }
}

// ---------------- init ----------------
__global__ void init_k(int* __restrict__ tok, int* __restrict__ counts, int* __restrict__ cursors) {
  int i = blockIdx.x * blockDim.x + threadIdx.x;
  if (i < PMAX) tok[i] = -1;
  if (i < NEXP) { counts[i] = 0; cursors[i] = 0; }
}

// ---------------- router (fused x->bf16 conversion) ----------------
__global__ __launch_bounds__(256) void router_k(const float4* __restrict__ x4,
                                                const float4* __restrict__ rw4,
                                                ushort4* __restrict__ xb4,
                                                float* __restrict__ wgt,
                                                int* __restrict__ eid,
                                                int* __restrict__ counts) {
  int lane = threadIdx.x & 63;
  int wv = threadIdx.x >> 6;
  int t = blockIdx.x * 4 + wv;
  int base = t * (DDIM / 4);
  float acc[NEXP];
#pragma unroll
  for (int e = 0; e < NEXP; ++e) acc[e] = 0.f;
#pragma unroll
  for (int j = 0; j < DDIM / 4 / 64; ++j) {
    float4 v = x4[base + j * 64 + lane];
    ushort4 o;
    o.x = f2bf(v.x); o.y = f2bf(v.y); o.z = f2bf(v.z); o.w = f2bf(v.w);
    xb4[base + j * 64 + lane] = o;
#pragma unroll
    for (int e = 0; e < NEXP; ++e) {
      float4 w = rw4[e * (DDIM / 4) + j * 64 + lane];
      acc[e] += v.x * w.x + v.y * w.y + v.z * w.z + v.w * w.w;
    }
  }
#pragma unroll
  for (int e = 0; e < NEXP; ++e) {
#pragma unroll
    for (int s = 32; s > 0; s >>= 1) acc[e] += __shfl_xor(acc[e], s, 64);
  }
  if (lane == 0) {
    float mx = acc[0];
#pragma unroll
    for (int e = 1; e < NEXP; ++e) mx = fmaxf(mx, acc[e]);
    float p[NEXP];
#pragma unroll
    for (int e = 0; e < NEXP; ++e) p[e] = expf(acc[e] - mx);
    int e0 = 0; float p0 = p[0];
#pragma unroll
    for (int e = 1; e < NEXP; ++e) if (p[e] > p0) { p0 = p[e]; e0 = e; }
    int e1 = -1; float p1 = -1.f;
#pragma unroll
    for (int e = 0; e < NEXP; ++e) if (e != e0 && p[e] > p1) { p1 = p[e]; e1 = e; }
    float s = p0 + p1;
    wgt[2 * t] = p0 / s; wgt[2 * t + 1] = p1 / s;
    eid[2 * t] = e0;     eid[2 * t + 1] = e1;
    atomicAdd(&counts[e0], 1);
    atomicAdd(&counts[e1], 1);
  }
}

// ---------------- offsets + tile map ----------------
__global__ void offsets_k(const int* __restrict__ counts, int* __restrict__ offs,
                          int* __restrict__ tile2exp, int* __restrict__ tilerow,
                          int* __restrict__ ntiles) {
  if (threadIdx.x == 0 && blockIdx.x == 0) {
    int o = 0, nt = 0;
    for (int e = 0; e < NEXP; ++e) {
      offs[e] = o;
      int c = counts[e];
      int pt = (c + 255) >> 8;
      for (int i = 0; i < pt; ++i) { tile2exp[nt] = e; tilerow[nt] = o + i * 256; ++nt; }
      o += pt << 8;
    }
    offs[NEXP] = o;
    ntiles[0] = nt;
  }
}

// ---------------- scatter ----------------
__global__ void scatter_k(const int* __restrict__ eid, const int* __restrict__ offs,
                          int* __restrict__ cursors, int* __restrict__ tok,
                          int* __restrict__ slot) {
  int t = blockIdx.x * blockDim.x + threadIdx.x;
  if (t >= M_TOK) return;
#pragma unroll
  for (int k = 0; k < 2; ++k) {
    int e = eid[2 * t + k];
    int p = offs[e] + atomicAdd(&cursors[e], 1);
    tok[p] = t;
    slot[2 * t + k] = p;
  }
}

// =============== GEMM1: 256 slots x (128 gate + 128 up), K=2048 ===============
__global__ __launch_bounds__(512, 1) void gemm1_k(const unsigned short* __restrict__ xb,
                                                  const unsigned short* __restrict__ w1b,
                                                  const int* __restrict__ tok,
                                                  const int* __restrict__ tile2exp,
                                                  const int* __restrict__ tilerow,
                                                  const int* __restrict__ ntiles,
                                                  unsigned short* __restrict__ h) {
  __shared__ char ldsp[131072];
  int mt = blockIdx.x;
  if (mt >= ntiles[0]) return;
  int e = tile2exp[mt], r0 = tilerow[mt];
  int n0 = blockIdx.y * 128;
  int tid = threadIdx.x, lane = tid & 63;
  int wv = tid >> 6, wm = wv >> 2, wn = wv & 3;
  int l15 = lane & 15, g = lane >> 4;

  // staging sources: thread owns slots tid (row0=tid>>2) and 512+tid (row0+128)
  // within each 16KB sub-buffer; source granule inverse-swizzled.
  int row0 = tid >> 2, g0 = (tid & 3) ^ ((row0 >> 1) & 3);
  int row1 = row0 + 128;
  int t0 = tok[r0 + row0]; if (t0 < 0) t0 = 0;
  int t1 = tok[r0 + row1]; if (t1 < 0) t1 = 0;
  const char* aS0 = (const char*)xb + (size_t)t0 * (DDIM * 2) + g0 * 16;
  const char* aS1 = (const char*)xb + (size_t)t1 * (DDIM * 2) + g0 * 16;
  size_t w1r0 = (size_t)e * (2 * HDIM) + (size_t)(n0 + row0);          // gate row
  size_t w1r1 = (size_t)e * (2 * HDIM) + (size_t)(HDIM + n0 + row0);   // up row
  const char* bS0 = (const char*)w1b + w1r0 * (DDIM * 2) + g0 * 16;
  const char* bS1 = (const char*)w1b + w1r1 * (DDIM * 2) + g0 * 16;

  int aoff[8], boff[4];
#pragma unroll
  for (int mi = 0; mi < 8; ++mi) {
    int r = wm * 128 + mi * 16 + l15;
    aoff[mi] = r * 64 + ((g ^ ((r >> 1) & 3)) << 4);
  }
#pragma unroll
  for (int ni = 0; ni < 4; ++ni) {
    int r = wn * 64 + ni * 16 + l15;
    boff[ni] = r * 64 + ((g ^ ((r >> 1) & 3)) << 4);
  }

  f32x4 acc[8][4];
#pragma unroll
  for (int mi = 0; mi < 8; ++mi)
#pragma unroll
    for (int ni = 0; ni < 4; ++ni) acc[mi][ni] = (f32x4)(0.f);

  short8 av[4], bv[4];

  // prologue: K0 complete + K1 {B-Klo, A-Klo, B-Khi}; A-Khi(1) comes at (0,0)
  STGA(0, 0, 0); STGB(0, 0, 0); STGA(0, 0, 1); STGB(0, 0, 1);
  STGB(1, 1, 0); STGA(1, 1, 0); STGB(1, 1, 1);
  VMCNT(6);
  __builtin_amdgcn_s_barrier();

#pragma unroll 1
  for (int t = 0; t < NKT1 - 2; t += 2) {
    KTILE(t, 0, 1, 1, 1, 1, 6);
    KTILE(t + 1, 1, 1, 1, 1, 1, 6);
  }
  KTILE(NKT1 - 2, 0, 1, 0, 0, 0, 0);
  KTILE(NKT1 - 1, 1, 0, 0, 0, 0, 0);

  // epilogue: cross-wave GLU pairing through LDS (f32 [256][128], XOR-swizzled)
  __syncthreads();
  float* xch = (float*)ldsp;
  int rbase = (lane >> 4) * 4;
  if (wn >= 2) {
    int uc0 = (wn - 2) * 64;
#pragma unroll
    for (int mi = 0; mi < 8; ++mi)
#pragma unroll
      for (int ni = 0; ni < 4; ++ni)
#pragma unroll
        for (int j = 0; j < 4; ++j) {
          int r = wm * 128 + mi * 16 + rbase + j;
          int c = uc0 + ni * 16 + l15;
          int cs = c ^ ((r & 3) << 2) ^ ((r & 1) << 4);
          xch[r * 128 + cs] = acc[mi][ni][j];
        }
  }
  __syncthreads();
  if (wn < 2) {
#pragma unroll
    for (int mi = 0; mi < 8; ++mi)
#pragma unroll
      for (int ni = 0; ni < 4; ++ni)
#pragma unroll
        for (int j = 0; j < 4; ++j) {
          int r = wm * 128 + mi * 16 + rbase + j;
          int c = wn * 64 + ni * 16 + l15;
          int cs = c ^ ((r & 3) << 2) ^ ((r & 1) << 4);
          float gg = acc[mi][ni][j];
          float u = xch[r * 128 + cs];
          float sv = gg / (1.f + expf(-gg));
          h[(size_t)(r0 + r) * HDIM + n0 + c] = f2bf(sv * u);
        }
  }
}

// =============== GEMM2: 256 slots x 256 D-cols, K=2816, yp bf16 ===============
__global__ __launch_bounds__(512, 1) void gemm2_k(const unsigned short* __restrict__ h,
                                                  const unsigned short* __restrict__ w2b,
                                                  const int* __restrict__ tile2exp,
                                                  const int* __restrict__ tilerow,
                                                  const int* __restrict__ ntiles,
                                                  unsigned short* __restrict__ yp) {
  __shared__ char ldsp[131072];
  int mt = blockIdx.x;
  if (mt >= ntiles[0]) return;
  int e = tile2exp[mt], r0 = tilerow[mt];
  int n0 = blockIdx.y * 256;
  int tid = threadIdx.x, lane = tid & 63;
  int wv = tid >> 6, wm = wv >> 2, wn = wv & 3;
  int l15 = lane & 15, g = lane >> 4;

  int row0 = tid >> 2, g0 = (tid & 3) ^ ((row0 >> 1) & 3);
  int row1 = row0 + 128;
  const char* aS0 = (const char*)h + (size_t)(r0 + row0) * (HDIM * 2) + g0 * 16;
  const char* aS1 = (const char*)h + (size_t)(r0 + row1) * (HDIM * 2) + g0 * 16;
  const char* bS0 = (const char*)w2b + ((size_t)e * DDIM + n0 + row0) * (HDIM * 2) + g0 * 16;
  const char* bS1 = (const char*)w2b + ((size_t)e * DDIM + n0 + row1) * (HDIM * 2) + g0 * 16;

  int aoff[8], boff[4];
#pragma unroll
  for (int mi = 0; mi < 8; ++mi) {
    int r = wm * 128 + mi * 16 + l15;
    aoff[mi] = r * 64 + ((g ^ ((r >> 1) & 3)) << 4);
  }
#pragma unroll
  for (int ni = 0; ni < 4; ++ni) {
    int r = wn * 64 + ni * 16 + l15;
    boff[ni] = r * 64 + ((g ^ ((r >> 1) & 3)) << 4);
  }

  f32x4 acc[8][4];
#pragma unroll
  for (int mi = 0; mi < 8; ++mi)
#pragma unroll
    for (int ni = 0; ni < 4; ++ni) acc[mi][ni] = (f32x4)(0.f);

  short8 av[4], bv[4];

  STGA(0, 0, 0); STGB(0, 0, 0); STGA(0, 0, 1); STGB(0, 0, 1);
  STGB(1, 1, 0); STGA(1, 1, 0); STGB(1, 1, 1);
  VMCNT(6);
  __builtin_amdgcn_s_barrier();

#pragma unroll 1
  for (int t = 0; t < NKT2 - 2; t += 2) {
    KTILE(t, 0, 1, 1, 1, 1, 6);
    KTILE(t + 1, 1, 1, 1, 1, 1, 6);
  }
  KTILE(NKT2 - 2, 0, 1, 0, 0, 0, 0);
  KTILE(NKT2 - 1, 1, 0, 0, 0, 0, 0);

  int rbase = (lane >> 4) * 4;
#pragma unroll
  for (int mi = 0; mi < 8; ++mi)
#pragma unroll
    for (int ni = 0; ni < 4; ++ni)
#pragma unroll
      for (int j = 0; j < 4; ++j) {
        int r = r0 + wm * 128 + mi * 16 + rbase + j;
        int c = n0 + wn * 64 + ni * 16 + l15;
        yp[(size_t)r * DDIM + c] = f2bf(acc[mi][ni][j]);
      }
}

// ---------------- combine: y = w0*yp[s0] + w1*yp[s1] + bias ----------------
__global__ void combine_k(const unsigned short* __restrict__ yp, const float* __restrict__ wgt,
                          const int* __restrict__ slot, const float* __restrict__ bias,
                          float* __restrict__ out) {
  int idx = blockIdx.x * blockDim.x + threadIdx.x;
  int t = idx >> 8, q = (idx & 255) * 8;
  float w0 = wgt[2 * t], w1 = wgt[2 * t + 1];
  int s0 = slot[2 * t], s1 = slot[2 * t + 1];
  short8 a8 = *(const short8*)(yp + (size_t)s0 * DDIM + q);
  short8 b8 = *(const short8*)(yp + (size_t)s1 * DDIM + q);
  float* op = out + (size_t)t * DDIM + q;
#pragma unroll
  for (int k = 0; k < 8; ++k) {
    float av = bf2f((unsigned short)a8[k]);
    float bv = bf2f((unsigned short)b8[k]);
    op[k] = w0 * av + w1 * bv + bias[q + k];
  }
}

extern "C" void kernel_launch(void* const* d_in, const int* in_sizes, int n_in,
                              void* d_out, int out_size, void* d_ws, size_t ws_size,
                              hipStream_t stream) {
  const float* x    = (const float*)d_in[0];
  const float* w1   = (const float*)d_in[1];
  const float* w2   = (const float*)d_in[2];
  const float* rw   = (const float*)d_in[3];
  const float* bias = (const float*)d_in[4];
  float* out = (float*)d_out;

  char* ws = (char*)d_ws;
  size_t off = 0;
  auto alloc = [&](size_t bytes) -> void* {
    void* p = ws + off;
    off = (off + bytes + 255) & ~(size_t)255;
    return p;
  };
  unsigned short* w1b = (unsigned short*)alloc((size_t)NEXP * 2 * HDIM * DDIM * 2);
  unsigned short* w2b = (unsigned short*)alloc((size_t)NEXP * DDIM * HDIM * 2);
  unsigned short* xb  = (unsigned short*)alloc((size_t)M_TOK * DDIM * 2);
  unsigned short* h   = (unsigned short*)alloc((size_t)PMAX * HDIM * 2);
  unsigned short* yp  = (unsigned short*)alloc((size_t)PMAX * DDIM * 2);
  float* wgt          = (float*)alloc((size_t)M_TOK * 2 * 4);
  int* eid            = (int*)alloc((size_t)M_TOK * 2 * 4);
  int* slot           = (int*)alloc((size_t)M_TOK * 2 * 4);
  int* tok            = (int*)alloc((size_t)PMAX * 4);
  int* counts         = (int*)alloc(64 * 4);
  int* cursors        = (int*)alloc(64 * 4);
  int* offs           = (int*)alloc(64 * 4);
  int* ntiles         = (int*)alloc(64 * 4);
  int* tile2exp       = (int*)alloc(128 * 4);
  int* tilerow        = (int*)alloc(128 * 4);

  hipLaunchKernelGGL(init_k, dim3((PMAX + 255) / 256), dim3(256), 0, stream, tok, counts, cursors);
  hipLaunchKernelGGL(cvt_bf16_k, dim3(2048), dim3(256), 0, stream,
                     (const float4*)w1, (ushort4*)w1b, (int)((size_t)NEXP * 2 * HDIM * DDIM / 4));
  hipLaunchKernelGGL(cvt_bf16_k, dim3(2048), dim3(256), 0, stream,
                     (const float4*)w2, (ushort4*)w2b, (int)((size_t)NEXP * DDIM * HDIM / 4));
  hipLaunchKernelGGL(router_k, dim3(M_TOK / 4), dim3(256), 0, stream,
                     (const float4*)x, (const float4*)rw, (ushort4*)xb, wgt, eid, counts);
  hipLaunchKernelGGL(offsets_k, dim3(1), dim3(64), 0, stream, counts, offs,
                     tile2exp, tilerow, ntiles);
  hipLaunchKernelGGL(scatter_k, dim3((M_TOK + 255) / 256), dim3(256), 0, stream, eid, offs, cursors, tok, slot);
  hipLaunchKernelGGL(gemm1_k, dim3(MAXTILES, NB1), dim3(512), 0, stream,
                     xb, w1b, tok, tile2exp, tilerow, ntiles, h);
  hipLaunchKernelGGL(gemm2_k, dim3(MAXTILES, NB2), dim3(512), 0, stream,
                     h, w2b, tile2exp, tilerow, ntiles, yp);
  hipLaunchKernelGGL(combine_k, dim3(M_TOK * (DDIM / 8) / 256), dim3(256), 0, stream, yp, wgt, slot, bias, out);
}